// Round 3
// baseline (700.023 us; speedup 1.0000x reference)
//
#include <hip/hip_runtime.h>

#define NG   16       // groups
#define CG   16       // channels per group
#define NB   64       // batch
#define CC   256      // channels
#define HW   3136     // 56*56
#define HW4  784      // HW/4
#define MTOT (NB*HW)  // 200704 samples per channel
#define Q4   (NB*HW4) // 50176 float4-quads per channel
#define EPSV 1e-3f
#define NTRI 136      // 16*17/2 upper-triangular entries
#define NRED (CG+NTRI) // 152 reduced values per group

// clang native vector type for nontemporal stores (HIP float4 is a class
// type __builtin_nontemporal_store rejects).
typedef float vfloat4 __attribute__((ext_vector_type(4)));

// ws layout (floats):
//   [0,256)        chsum   per-channel sums (atomic accumulated)
//   [256,2432)     cross   per-group triangular second moments (16*136)
//   [2432,6528)    wmw     per-group scaled whitening matrix (16*256)
//   [6528,6784)    ob      per-channel fused offset
//   [6784,6788)    barrier counters (2 x unsigned)
#define WS_CROSS 256
#define WS_WMW   2432
#define WS_OB    6528
#define WS_BAR   6784
#define WS_ZERO_BYTES ((WS_BAR + 8) * 4)

// R3: single persistent kernel. 256 blocks (1 per CU, co-resident by
// construction: 256 threads, <=512 VGPR -> exactly 1 block fits per CU,
// grid == CU count). Phases separated by a device-scope atomic barrier.
// Rationale: (a) the 3-kernel split was invisible in top-5 counters under
// the harness's 127us ws-poison fills -- fused we get our own counters;
// (b) kills two kernel-boundary drains; (c) apply gets the same
// double-buffered register prefetch as stats (1 wave/SIMD -> ILP is the
// only latency hiding available).
#define NBLK   256
#define TPG    4096          // threads per group (16 blocks * 256)
#define FULL_IT 12           // 12 full iters + tail (sb<4): 16*256*12.25 = Q4

__device__ __forceinline__ void grid_barrier(float* ws, int which) {
    __syncthreads();
    if (threadIdx.x == 0) {
        unsigned* ctr = (unsigned*)(ws + WS_BAR) + which;
        __threadfence();   // release: drain prior global writes/atomics
        __hip_atomic_fetch_add(ctr, 1u, __ATOMIC_RELEASE, __HIP_MEMORY_SCOPE_AGENT);
        while (__hip_atomic_load(ctr, __ATOMIC_ACQUIRE, __HIP_MEMORY_SCOPE_AGENT) < NBLK) {
            __builtin_amdgcn_s_sleep(2);
        }
    }
    __syncthreads();
}

__global__ __launch_bounds__(256, 1) void dbn_fused(const float* __restrict__ X,
                                                    const float* __restrict__ weight,
                                                    const float* __restrict__ bias,
                                                    float* __restrict__ out,
                                                    float* __restrict__ ws) {
    // g = bid & 15 so the 16 newton blocks (bid < 16) spread across XCDs.
    const int bid = blockIdx.x;
    const int g   = bid & 15;          // group
    const int sb  = bid >> 4;          // sub-block within group [0,16)
    const int tid = threadIdx.x;
    const int q0  = sb * 256 + tid;    // [0, 4096)
    const int gq  = g * CG * HW4;      // group channel offset (quads)
    const bool tail = (sb < 4);        // uniform per block

    const float4* __restrict__ X4 = (const float4*)X;

    __shared__ float part[4][NRED];
    __shared__ float Y[CG][CG + 1], Z[CG][CG + 1], T[CG][CG + 1];
    __shared__ float mean_s[CG];
    __shared__ float red[256];
    __shared__ float s_norm;
    __shared__ float wmw_s[CG][CG];
    __shared__ float ob_s[CG];

    // ---------------- Phase 1: per-group covariance stats ----------------
    {
        float cross[NTRI];
        float csum[CG];
#pragma unroll
        for (int i = 0; i < NTRI; ++i) cross[i] = 0.f;
#pragma unroll
        for (int c = 0; c < CG; ++c) csum[c] = 0.f;

        float4 va[CG], vb[CG];

#define LOADV(V, QQ)                                                       \
    {                                                                      \
        const int q4_ = (QQ);                                              \
        const int n_  = q4_ / HW4;                                         \
        const int p4_ = q4_ - n_ * HW4;                                    \
        const float4* __restrict__ pp_ = X4 + n_ * (CC * HW4) + gq + p4_;  \
        _Pragma("unroll")                                                  \
        for (int c_ = 0; c_ < CG; ++c_) V[c_] = pp_[c_ * HW4];             \
    }

#define ACCV(V)                                                            \
    {                                                                      \
        _Pragma("unroll")                                                  \
        for (int c_ = 0; c_ < CG; ++c_)                                    \
            csum[c_] += (V[c_].x + V[c_].y) + (V[c_].z + V[c_].w);         \
        int i_ = 0;                                                        \
        _Pragma("unroll")                                                  \
        for (int c_ = 0; c_ < CG; ++c_) {                                  \
            _Pragma("unroll")                                              \
            for (int d_ = c_; d_ < CG; ++d_, ++i_)                         \
                cross[i_] += V[c_].x * V[d_].x + V[c_].y * V[d_].y +       \
                             V[c_].z * V[d_].z + V[c_].w * V[d_].w;        \
        }                                                                  \
    }

        LOADV(va, q0);
#pragma unroll 1
        for (int p = 0; p < FULL_IT / 2 - 1; ++p) {     // iters 0..9
            LOADV(vb, q0 + (2 * p + 1) * TPG);
            ACCV(va);
            LOADV(va, q0 + (2 * p + 2) * TPG);
            ACCV(vb);
        }
        LOADV(vb, q0 + 11 * TPG);
        ACCV(va);                                        // iter 10
        if (tail) LOADV(va, q0 + FULL_IT * TPG);
        ACCV(vb);                                        // iter 11
        if (tail) ACCV(va);                              // iter 12 (tail)

#undef LOADV
#undef ACCV

        const int lane = tid & 63;
        const int w    = tid >> 6;
#pragma unroll
        for (int c = 0; c < CG; ++c) {
            float v = csum[c];
            v += __shfl_xor(v, 32); v += __shfl_xor(v, 16); v += __shfl_xor(v, 8);
            v += __shfl_xor(v, 4);  v += __shfl_xor(v, 2);  v += __shfl_xor(v, 1);
            csum[c] = v;
        }
#pragma unroll
        for (int i = 0; i < NTRI; ++i) {
            float v = cross[i];
            v += __shfl_xor(v, 32); v += __shfl_xor(v, 16); v += __shfl_xor(v, 8);
            v += __shfl_xor(v, 4);  v += __shfl_xor(v, 2);  v += __shfl_xor(v, 1);
            cross[i] = v;
        }

        if (lane == 0) {
#pragma unroll
            for (int c = 0; c < CG; ++c) part[w][c] = csum[c];
#pragma unroll
            for (int i = 0; i < NTRI; ++i) part[w][CG + i] = cross[i];
        }
        __syncthreads();
        if (tid < NRED) {
            float s = part[0][tid] + part[1][tid] + part[2][tid] + part[3][tid];
            if (tid < CG) atomicAdd(&ws[g * CG + tid], s);
            else          atomicAdd(&ws[WS_CROSS + g * NTRI + (tid - CG)], s);
        }
    }

    grid_barrier(ws, 0);

    // ---------------- Phase 2: Newton-Schulz (blocks 0..15 only) ----------------
    if (bid < NG) {
        const int gg = bid;
        const int c  = tid >> 4;
        const int d  = tid & 15;

        if (tid < CG)
            mean_s[tid] = __hip_atomic_load(&ws[gg * CG + tid], __ATOMIC_RELAXED,
                                            __HIP_MEMORY_SCOPE_AGENT) * (1.0f / MTOT);
        __syncthreads();

        const int cc = min(c, d), dd = max(c, d);
        const int idx = cc * CG + dd - (cc * (cc + 1)) / 2;
        float sig = __hip_atomic_load(&ws[WS_CROSS + gg * NTRI + idx], __ATOMIC_RELAXED,
                                      __HIP_MEMORY_SCOPE_AGENT) * (1.0f / MTOT)
                  - mean_s[c] * mean_s[d] + ((c == d) ? EPSV : 0.f);

        red[tid] = sig * sig;
        __syncthreads();
        for (int s = 128; s > 0; s >>= 1) {
            if (tid < s) red[tid] += red[tid + s];
            __syncthreads();
        }
        if (tid == 0) s_norm = sqrtf(red[0]);
        __syncthreads();
        const float s = s_norm;

        Y[c][d] = sig / s;
        Z[c][d] = (c == d) ? 1.f : 0.f;
        __syncthreads();

        for (int itn = 0; itn < 12; ++itn) {
            float t = 0.f;
#pragma unroll
            for (int k = 0; k < CG; ++k) t += Z[c][k] * Y[k][d];
            t = ((c == d) ? 3.f : 0.f) - t;
            __syncthreads();
            T[c][d] = t;
            __syncthreads();
            float yn = 0.f, zn = 0.f;
#pragma unroll
            for (int k = 0; k < CG; ++k) {
                yn += Y[c][k] * T[k][d];
                zn += T[c][k] * Z[k][d];
            }
            __syncthreads();
            Y[c][d] = 0.5f * yn;
            Z[c][d] = 0.5f * zn;
            __syncthreads();
        }

        const float wm  = Z[c][d] / sqrtf(s);
        const float w   = weight[gg * CG + c];
        const float wmw = wm * w;
        __hip_atomic_store(&ws[WS_WMW + gg * 256 + c * CG + d], wmw,
                           __ATOMIC_RELAXED, __HIP_MEMORY_SCOPE_AGENT);

        T[c][d] = wmw * mean_s[d];
        __syncthreads();
        if (d == 0) {
            float acc = 0.f;
#pragma unroll
            for (int k = 0; k < CG; ++k) acc += T[c][k];
            __hip_atomic_store(&ws[WS_OB + gg * CG + c], bias[gg * CG + c] - acc,
                               __ATOMIC_RELAXED, __HIP_MEMORY_SCOPE_AGENT);
        }
    }

    grid_barrier(ws, 1);

    // ---------------- Phase 3: apply whitening ----------------
    {
        // agent-scope atomic loads: bypass possibly-stale per-XCD L2 copies
        wmw_s[tid >> 4][tid & 15] = __hip_atomic_load(&ws[WS_WMW + g * 256 + tid],
                                                      __ATOMIC_RELAXED,
                                                      __HIP_MEMORY_SCOPE_AGENT);
        if (tid < CG)
            ob_s[tid] = __hip_atomic_load(&ws[WS_OB + g * CG + tid],
                                          __ATOMIC_RELAXED, __HIP_MEMORY_SCOPE_AGENT);
        __syncthreads();

        vfloat4* __restrict__ O4 = (vfloat4*)out;
        float4 pa[CG], pb[CG];

#define LOADA(V, QQ)                                                       \
    {                                                                      \
        const int q4_ = (QQ);                                              \
        const int n_  = q4_ / HW4;                                         \
        const int p4_ = q4_ - n_ * HW4;                                    \
        const float4* __restrict__ pp_ = X4 + n_ * (CC * HW4) + gq + p4_;  \
        _Pragma("unroll")                                                  \
        for (int c_ = 0; c_ < CG; ++c_) V[c_] = pp_[c_ * HW4];             \
    }

#define APPV(V, QQ)                                                        \
    {                                                                      \
        const int q4_ = (QQ);                                              \
        const int n_  = q4_ / HW4;                                         \
        const int p4_ = q4_ - n_ * HW4;                                    \
        const int base_ = n_ * (CC * HW4) + gq + p4_;                      \
        _Pragma("unroll")                                                  \
        for (int c_ = 0; c_ < CG; ++c_) {                                  \
            const float o_ = ob_s[c_];                                     \
            vfloat4 acc_;                                                  \
            acc_.x = o_; acc_.y = o_; acc_.z = o_; acc_.w = o_;            \
            _Pragma("unroll")                                              \
            for (int d_ = 0; d_ < CG; ++d_) {                              \
                const float w_ = wmw_s[c_][d_];                            \
                acc_.x += w_ * V[d_].x; acc_.y += w_ * V[d_].y;            \
                acc_.z += w_ * V[d_].z; acc_.w += w_ * V[d_].w;            \
            }                                                              \
            __builtin_nontemporal_store(acc_, &O4[base_ + c_ * HW4]);      \
        }                                                                  \
    }

        LOADA(pa, q0);
#pragma unroll 1
        for (int p = 0; p < FULL_IT / 2 - 1; ++p) {     // iters 0..9
            LOADA(pb, q0 + (2 * p + 1) * TPG);
            APPV(pa, q0 + (2 * p) * TPG);
            LOADA(pa, q0 + (2 * p + 2) * TPG);
            APPV(pb, q0 + (2 * p + 1) * TPG);
        }
        LOADA(pb, q0 + 11 * TPG);
        APPV(pa, q0 + 10 * TPG);
        if (tail) LOADA(pa, q0 + FULL_IT * TPG);
        APPV(pb, q0 + 11 * TPG);
        if (tail) APPV(pa, q0 + FULL_IT * TPG);

#undef LOADA
#undef APPV
    }
}

extern "C" void kernel_launch(void* const* d_in, const int* in_sizes, int n_in,
                              void* d_out, int out_size, void* d_ws, size_t ws_size,
                              hipStream_t stream) {
    const float* X      = (const float*)d_in[0];
    const float* weight = (const float*)d_in[1];
    const float* bias   = (const float*)d_in[2];
    float* out = (float*)d_out;
    float* ws  = (float*)d_ws;

    // zero accumulators + barrier counters (ws is poisoned 0xAA each call)
    (void)hipMemsetAsync(ws, 0, WS_ZERO_BYTES, stream);

    dbn_fused<<<dim3(NBLK), 256, 0, stream>>>(X, weight, bias, out, ws);
}